// Round 1
// baseline (16.500 us; speedup 1.0000x reference)
//
#include <hip/hip_runtime.h>

#define NB 8
#define T_IN 512
#define D 384
#define D4 96           // D/4
#define T_MEL 3584
#define MEL_MAX 2048

// ---------------------------------------------------------------------------
// Kernel A: one block per batch. Scan durations -> token boundaries,
// write dec_lens (as float), compute pitch averages, and scatter a
// frame->token map into workspace for the gather kernel.
// ---------------------------------------------------------------------------
__global__ __launch_bounds__(T_IN) void fp_scan_kernel(
    const int* __restrict__ dur,
    const float* __restrict__ pitch,
    float* __restrict__ out,
    int* __restrict__ map)
{
    const int b = blockIdx.x;
    const int t = threadIdx.x;
    __shared__ int s[T_IN];

    // init frame->token map to -1 (tail frames must produce zeros)
    const int base = b * MEL_MAX;
    for (int m = t; m < MEL_MAX; m += T_IN) map[base + m] = -1;

    // reps = floor(dur/PACE + 0.5) = dur  (PACE == 1.0, integer dur)
    const int d = dur[b * T_IN + t];
    s[t] = d;
    __syncthreads();
    // Hillis-Steele inclusive scan over 512 tokens
    for (int off = 1; off < T_IN; off <<= 1) {
        int v = (t >= off) ? s[t - off] : 0;
        __syncthreads();
        s[t] += v;
        __syncthreads();
    }
    const int end   = s[t];
    const int start = end - d;
    const int total = s[T_IN - 1];

    if (t == 0) {
        out[(size_t)NB * MEL_MAX * D + b] =
            (float)(total < MEL_MAX ? total : MEL_MAX);
    }

    // scatter token index for frames [start, min(end, MEL_MAX))
    const int e2 = end < MEL_MAX ? end : MEL_MAX;
    for (int m = start; m < e2; ++m) map[base + m] = t;

    // pitch average over frames [start, end) of pitch[b, 0, :]
    const float* p = pitch + (size_t)b * T_MEL;
    float acc = 0.0f;
    int cnt = 0;
    for (int m = start; m < end; ++m) {
        float v = p[m];
        acc += v;
        cnt += (v != 0.0f) ? 1 : 0;
    }
    out[(size_t)NB * MEL_MAX * D + NB + b * T_IN + t] =
        cnt ? acc / (float)cnt : 0.0f;
}

// ---------------------------------------------------------------------------
// Kernel B: gather enc_rep. One float4 per thread over the whole
// [B, MEL_MAX, D] output; frame->token lookup via the map.
// ---------------------------------------------------------------------------
__global__ __launch_bounds__(256) void fp_gather_kernel(
    const float4* __restrict__ enc4,
    const int* __restrict__ map,
    float4* __restrict__ out4)
{
    const int idx = blockIdx.x * 256 + threadIdx.x;   // float4 index
    const int total4 = NB * MEL_MAX * D4;             // 1,572,864
    if (idx >= total4) return;
    const int frame = idx / D4;          // b*MEL_MAX + m
    const int d4    = idx - frame * D4;
    const int tok   = map[frame];
    float4 v = make_float4(0.0f, 0.0f, 0.0f, 0.0f);
    if (tok >= 0) {
        const int b = frame >> 11;       // frame / MEL_MAX
        v = enc4[(size_t)(b * T_IN + tok) * D4 + d4];
    }
    out4[idx] = v;
}

extern "C" void kernel_launch(void* const* d_in, const int* in_sizes, int n_in,
                              void* d_out, int out_size, void* d_ws, size_t ws_size,
                              hipStream_t stream) {
    const float* enc   = (const float*)d_in[0];
    const int*   dur   = (const int*)d_in[1];
    const float* pitch = (const float*)d_in[2];
    float* out = (float*)d_out;
    int*   map = (int*)d_ws;   // NB*MEL_MAX ints = 64 KB

    fp_scan_kernel<<<NB, T_IN, 0, stream>>>(dur, pitch, out, map);

    const int total4 = NB * MEL_MAX * D4;
    fp_gather_kernel<<<total4 / 256, 256, 0, stream>>>(
        (const float4*)enc, map, (float4*)out);
}

// Round 3
// 15.888 us; speedup vs baseline: 1.0385x; 1.0385x over previous
//
#include <hip/hip_runtime.h>

typedef float floatx4 __attribute__((ext_vector_type(4)));

#define NB 8
#define T_IN 512
#define D 384
#define D4 96            // D/4
#define T_MEL 3584
#define MEL_MAX 2048

#define MAP_SIZE (NB * MEL_MAX)            // ints at ws offset 0
#define ENDS_OFF MAP_SIZE                  // token inclusive-cumsum ends, NB*T_IN ints
#define DEC_OFF  ((size_t)NB * MEL_MAX * D)        // dec_lens offset in out
#define PITCH_OFF (DEC_OFF + NB)                   // pitch_avg offset in out

#define GATHER_BLOCKS ((NB * MEL_MAX * D4) / 256)  // 6144
#define PITCH_BLOCKS  ((NB * T_IN) / 256)          // 16

// ---------------------------------------------------------------------------
// Kernel A: one block per batch. Wave-shuffle scan of durations -> token
// boundaries; write dec_lens (float), token ends (ws), frame->token map
// (tail = -1). PACE==1.0 so reps == dur.
// ---------------------------------------------------------------------------
__global__ __launch_bounds__(T_IN) void fp_scan_kernel(
    const int* __restrict__ dur,
    float* __restrict__ out,
    int* __restrict__ ws)
{
    const int b = blockIdx.x;
    const int t = threadIdx.x;
    const int lane = t & 63;
    const int w = t >> 6;          // wave id, 0..7
    __shared__ int wsum[8];

    const int d = dur[b * T_IN + t];
    int x = d;
    #pragma unroll
    for (int off = 1; off < 64; off <<= 1) {
        int y = __shfl_up(x, off, 64);
        if (lane >= off) x += y;   // wave-inclusive scan
    }
    if (lane == 63) wsum[w] = x;
    __syncthreads();

    int woff = 0, total = 0;
    #pragma unroll
    for (int i = 0; i < 8; ++i) {
        int v = wsum[i];
        if (i < w) woff += v;
        total += v;
    }
    const int end   = woff + x;    // inclusive cumsum
    const int start = end - d;

    ws[ENDS_OFF + b * T_IN + t] = end;
    if (t == 0)
        out[DEC_OFF + b] = (float)(total < MEL_MAX ? total : MEL_MAX);

    int* map = ws + b * MEL_MAX;
    // tail frames [min(total,MEL_MAX), MEL_MAX) -> -1 (produce zeros)
    const int tot2 = total < MEL_MAX ? total : MEL_MAX;
    for (int m = tot2 + t; m < MEL_MAX; m += T_IN) map[m] = -1;
    // frames [start, min(end,MEL_MAX)) -> token t
    const int e2 = end < MEL_MAX ? end : MEL_MAX;
    for (int m = start; m < e2; ++m) map[m] = t;
}

// ---------------------------------------------------------------------------
// Kernel B: blocks [0, GATHER_BLOCKS) gather enc_rep (1 float4/thread,
// nontemporal streaming stores). Blocks [GATHER_BLOCKS, +PITCH_BLOCKS)
// compute pitch averages (1 token/thread) from ws ends.
// ---------------------------------------------------------------------------
__global__ __launch_bounds__(256) void fp_main_kernel(
    const floatx4* __restrict__ enc4,
    const float* __restrict__ pitch,
    const int* __restrict__ dur,
    const int* __restrict__ ws,
    float* __restrict__ out)
{
    const int bid = blockIdx.x;
    if (bid < GATHER_BLOCKS) {
        const unsigned idx = bid * 256u + threadIdx.x;   // float4 index
        const unsigned frame = idx / D4;                 // b*MEL_MAX + m
        const unsigned d4 = idx - frame * D4;
        const int tok = ws[frame];                       // map
        floatx4 v = (floatx4)(0.0f);
        if (tok >= 0) {
            const unsigned b = frame >> 11;              // / MEL_MAX
            v = enc4[(size_t)(b * T_IN + tok) * D4 + d4];
        }
        __builtin_nontemporal_store(v, (floatx4*)out + idx);
    } else {
        const int idx = (bid - GATHER_BLOCKS) * 256 + threadIdx.x; // 0..4095
        const int b = idx >> 9;
        const int t = idx & (T_IN - 1);
        const int end = ws[ENDS_OFF + idx];
        const int start = end - dur[idx];
        const float* p = pitch + (size_t)b * T_MEL;
        float acc = 0.0f;
        int cnt = 0;
        for (int m = start; m < end; ++m) {
            float v = p[m];
            acc += v;
            cnt += (v != 0.0f) ? 1 : 0;
        }
        out[PITCH_OFF + idx] = cnt ? acc / (float)cnt : 0.0f;
    }
}

extern "C" void kernel_launch(void* const* d_in, const int* in_sizes, int n_in,
                              void* d_out, int out_size, void* d_ws, size_t ws_size,
                              hipStream_t stream) {
    const float* enc   = (const float*)d_in[0];
    const int*   dur   = (const int*)d_in[1];
    const float* pitch = (const float*)d_in[2];
    float* out = (float*)d_out;
    int*   ws  = (int*)d_ws;   // map (64 KB) + ends (16 KB)

    fp_scan_kernel<<<NB, T_IN, 0, stream>>>(dur, out, ws);
    fp_main_kernel<<<GATHER_BLOCKS + PITCH_BLOCKS, 256, 0, stream>>>(
        (const floatx4*)enc, pitch, dur, ws, out);
}

// Round 4
// 13.225 us; speedup vs baseline: 1.2477x; 1.2014x over previous
//
#include <hip/hip_runtime.h>

typedef float floatx4 __attribute__((ext_vector_type(4)));

#define NB 8
#define T_IN 512
#define D 384
#define D4 96            // D/4
#define T_MEL 3584
#define MEL_MAX 2048

#define FRAMES_PER_BLOCK 32
#define GB_PER_BATCH (MEL_MAX / FRAMES_PER_BLOCK)   // 64
#define GATHER_BLOCKS (NB * GB_PER_BATCH)           // 512
#define PITCH_BLOCKS  (NB * 2)                      // 2 blocks/batch, 256 tokens each

#define DEC_OFF  ((size_t)NB * MEL_MAX * D)         // dec_lens offset in out
#define PITCH_OFF (DEC_OFF + NB)                    // pitch_avg offset in out

// ---------------------------------------------------------------------------
// Single fused kernel. Every block redundantly scans its batch's 512
// durations (2 KB, L2-hot) -> token boundaries in LDS. PACE==1.0 so
// reps == dur; inclusive cumsum gives [start,end) per token.
//   blocks [0, 512):   gather enc_rep for 32 contiguous frames of one batch
//   blocks [512, 528): pitch averages (256 tokens each) + dec_lens
// ---------------------------------------------------------------------------
__global__ __launch_bounds__(256) void fp_fused_kernel(
    const int* __restrict__ dur,
    const floatx4* __restrict__ enc4,
    const float* __restrict__ pitch,
    float* __restrict__ out)
{
    const int bid = blockIdx.x;
    const int tid = threadIdx.x;
    const bool isPitch = bid >= GATHER_BLOCKS;
    const int b = isPitch ? ((bid - GATHER_BLOCKS) >> 1) : (bid / GB_PER_BATCH);

    __shared__ int s_ends[T_IN];
    __shared__ int s_wsum[4];
    __shared__ int s_map[FRAMES_PER_BLOCK];

    // ---- scan: 2 durations per thread, wave shuffle scan + wave offsets ----
    const int2 dd = ((const int2*)(dur + b * T_IN))[tid];   // dur[2t], dur[2t+1]
    int x = dd.x + dd.y;
    #pragma unroll
    for (int off = 1; off < 64; off <<= 1) {
        int y = __shfl_up(x, off, 64);
        if ((tid & 63) >= off) x += y;
    }
    if ((tid & 63) == 63) s_wsum[tid >> 6] = x;
    __syncthreads();
    int woff = 0, total = 0;
    #pragma unroll
    for (int i = 0; i < 4; ++i) {
        int v = s_wsum[i];
        if (i < (tid >> 6)) woff += v;
        total += v;
    }
    const int e1 = woff + x;            // inclusive end of token 2t+1
    s_ends[2 * tid]     = e1 - dd.y;    // inclusive end of token 2t
    s_ends[2 * tid + 1] = e1;
    __syncthreads();

    if (!isPitch) {
        const int f0 = (bid % GB_PER_BATCH) * FRAMES_PER_BLOCK;
        if (tid < FRAMES_PER_BLOCK) {
            const int f = f0 + tid;
            int tok = -1;
            if (f < total) {
                // upper_bound: smallest t with ends[t] > f
                int lo = 0, hi = T_IN;
                while (lo < hi) {
                    int mid = (lo + hi) >> 1;
                    if (s_ends[mid] > f) hi = mid; else lo = mid + 1;
                }
                tok = lo;               // < T_IN since f < total
            }
            s_map[tid] = tok;
        }
        if (tid == 0 && (bid % GB_PER_BATCH) == 0)
            out[DEC_OFF + b] = (float)(total < MEL_MAX ? total : MEL_MAX);
        __syncthreads();

        const floatx4* erow = enc4 + (size_t)b * T_IN * D4;
        floatx4* orow = (floatx4*)out + ((size_t)b * MEL_MAX + f0) * D4;
        #pragma unroll
        for (int it = 0; it < (FRAMES_PER_BLOCK * D4) / 256; ++it) {  // 12
            const int idx = it * 256 + tid;        // 0..3071 contiguous
            const int fl  = idx / D4;
            const int d4  = idx - fl * D4;
            const int tok = s_map[fl];
            floatx4 v = (floatx4)(0.0f);
            if (tok >= 0) v = erow[(size_t)tok * D4 + d4];
            __builtin_nontemporal_store(v, orow + idx);
        }
    } else {
        const int half = (bid - GATHER_BLOCKS) & 1;
        const int tk = half * 256 + tid;
        const int end   = s_ends[tk];
        const int start = tk ? s_ends[tk - 1] : 0;
        const float* p = pitch + (size_t)b * T_MEL;
        float acc = 0.0f;
        int cnt = 0;
        for (int m = start; m < end; ++m) {
            float v = p[m];
            acc += v;
            cnt += (v != 0.0f) ? 1 : 0;
        }
        out[PITCH_OFF + b * T_IN + tk] = cnt ? acc / (float)cnt : 0.0f;
    }
}

extern "C" void kernel_launch(void* const* d_in, const int* in_sizes, int n_in,
                              void* d_out, int out_size, void* d_ws, size_t ws_size,
                              hipStream_t stream) {
    const float* enc   = (const float*)d_in[0];
    const int*   dur   = (const int*)d_in[1];
    const float* pitch = (const float*)d_in[2];
    float* out = (float*)d_out;

    fp_fused_kernel<<<GATHER_BLOCKS + PITCH_BLOCKS, 256, 0, stream>>>(
        dur, (const floatx4*)enc, pitch, out);
}

// Round 5
// 11.834 us; speedup vs baseline: 1.3943x; 1.1175x over previous
//
#include <hip/hip_runtime.h>

typedef float floatx4 __attribute__((ext_vector_type(4)));

#define NB 8
#define T_IN 512
#define D 384
#define D4 96            // D/4
#define T_MEL 3584
#define MEL_MAX 2048

#define FRAMES_PER_BLOCK 16
#define GB_PER_BATCH (MEL_MAX / FRAMES_PER_BLOCK)   // 128
#define GATHER_BLOCKS (NB * GB_PER_BATCH)           // 1024
#define PITCH_BLOCKS  (NB * 2)                      // 2 blocks/batch, 256 tokens each

#define DEC_OFF  ((size_t)NB * MEL_MAX * D)         // dec_lens offset in out
#define PITCH_OFF (DEC_OFF + NB)                    // pitch_avg offset in out

// ---------------------------------------------------------------------------
// Single fused kernel. Every block redundantly scans its batch's 512
// durations (2 KB, L2-hot) -> token boundaries in LDS. PACE==1.0 so
// reps == dur; inclusive cumsum gives [start,end) per token.
//   blocks [0, 1024):   gather enc_rep for 16 contiguous frames of one batch
//   blocks [1024, 1040): pitch averages (256 tokens each) + dec_lens
// Plain (cacheable) stores: during timed replays the 25.2 MB output lives
// in L3, so HBM write traffic is only the eviction trickle.
// ---------------------------------------------------------------------------
__global__ __launch_bounds__(256) void fp_fused_kernel(
    const int* __restrict__ dur,
    const floatx4* __restrict__ enc4,
    const float* __restrict__ pitch,
    float* __restrict__ out)
{
    const int bid = blockIdx.x;
    const int tid = threadIdx.x;
    const bool isPitch = bid >= GATHER_BLOCKS;
    const int b = isPitch ? ((bid - GATHER_BLOCKS) >> 1) : (bid / GB_PER_BATCH);

    __shared__ int s_ends[T_IN];
    __shared__ int s_wsum[4];
    __shared__ int s_map[FRAMES_PER_BLOCK];

    // ---- scan: 2 durations per thread, wave shuffle scan + wave offsets ----
    const int2 dd = ((const int2*)(dur + b * T_IN))[tid];   // dur[2t], dur[2t+1]
    int x = dd.x + dd.y;
    #pragma unroll
    for (int off = 1; off < 64; off <<= 1) {
        int y = __shfl_up(x, off, 64);
        if ((tid & 63) >= off) x += y;
    }
    if ((tid & 63) == 63) s_wsum[tid >> 6] = x;
    __syncthreads();
    int woff = 0, total = 0;
    #pragma unroll
    for (int i = 0; i < 4; ++i) {
        int v = s_wsum[i];
        if (i < (tid >> 6)) woff += v;
        total += v;
    }
    const int e1 = woff + x;            // inclusive end of token 2t+1
    s_ends[2 * tid]     = e1 - dd.y;    // inclusive end of token 2t
    s_ends[2 * tid + 1] = e1;
    __syncthreads();

    if (!isPitch) {
        const int f0 = (bid % GB_PER_BATCH) * FRAMES_PER_BLOCK;
        if (tid < FRAMES_PER_BLOCK) {
            const int f = f0 + tid;
            int tok = -1;
            if (f < total) {
                // upper_bound: smallest t with ends[t] > f
                int lo = 0, hi = T_IN;
                while (lo < hi) {
                    int mid = (lo + hi) >> 1;
                    if (s_ends[mid] > f) hi = mid; else lo = mid + 1;
                }
                tok = lo;               // < T_IN since f < total
            }
            s_map[tid] = tok;
        }
        if (tid == 0 && bid == b * GB_PER_BATCH)
            out[DEC_OFF + b] = (float)(total < MEL_MAX ? total : MEL_MAX);
        __syncthreads();

        const floatx4* erow = enc4 + (size_t)b * T_IN * D4;
        floatx4* orow = (floatx4*)out + ((size_t)b * MEL_MAX + f0) * D4;
        #pragma unroll
        for (int it = 0; it < (FRAMES_PER_BLOCK * D4) / 256; ++it) {  // 6
            const int idx = it * 256 + tid;        // 0..1535 contiguous
            const int fl  = idx / D4;
            const int d4  = idx - fl * D4;
            const int tok = s_map[fl];
            floatx4 v = (floatx4)(0.0f);
            if (tok >= 0) v = erow[(size_t)tok * D4 + d4];
            orow[idx] = v;
        }
    } else {
        const int half = (bid - GATHER_BLOCKS) & 1;
        const int tk = half * 256 + tid;
        const int end   = s_ends[tk];
        const int start = tk ? s_ends[tk - 1] : 0;
        const float* p = pitch + (size_t)b * T_MEL;
        float acc = 0.0f;
        int cnt = 0;
        for (int m = start; m < end; ++m) {
            float v = p[m];
            acc += v;
            cnt += (v != 0.0f) ? 1 : 0;
        }
        out[PITCH_OFF + b * T_IN + tk] = cnt ? acc / (float)cnt : 0.0f;
    }
}

extern "C" void kernel_launch(void* const* d_in, const int* in_sizes, int n_in,
                              void* d_out, int out_size, void* d_ws, size_t ws_size,
                              hipStream_t stream) {
    const float* enc   = (const float*)d_in[0];
    const int*   dur   = (const int*)d_in[1];
    const float* pitch = (const float*)d_in[2];
    float* out = (float*)d_out;

    fp_fused_kernel<<<GATHER_BLOCKS + PITCH_BLOCKS, 256, 0, stream>>>(
        dur, (const floatx4*)enc, pitch, out);
}